// Round 8
// baseline (33.615 us; speedup 1.0000x reference)
//
#include <hip/hip_runtime.h>
#include <math.h>

// DifferentiableLogicLayer:
//   out[b,g] = sum_o ops(a,b)[o] * softmax(gate_logits[g])[o]
//   a = clip(x[b, g % 8192]), b = clip(x[b, (g+1) % 8192])
// All 16 ops are affine in {1, a, b, a*b}  ==>
//   out[b,g] = c0[g] + ca[g]*a + cb[g]*b + cab[g]*a*b
//
// R7 lesson: two-kernel at ~32us; main kernel runs ~3.8-4 TB/s effective,
// ~60% of copy ceiling. Hypothesis: per-wave MLP (~2 outstanding loads at
// VGPR=48) is the limiter. R8: load-all-then-compute — issue all 8 rows'
// loads (16 outstanding vmem/wave) before any compute/store. Single change
// vs R7 (clean A/B on MLP).

constexpr int INPUT_SIZE = 8192;
constexpr int NUM_GATES  = 8192;
constexpr int BATCH      = 2048;
constexpr int V4_PER_ROW = INPUT_SIZE / 4;     // 2048 float4 per row
constexpr int NBLOCKS    = 2048;               // 524288 threads
constexpr int ROW_STRIDE = 256;                // 524288 / 2048 col slots
constexpr int NITER      = BATCH / ROW_STRIDE; // 8 rows per thread

typedef float floatx4 __attribute__((ext_vector_type(4)));

// ---------------------------------------------------------------------------
// Kernel 1: fold softmax(gate_logits) into 4 affine coefficients per gate.
// ---------------------------------------------------------------------------
__global__ __launch_bounds__(256) void gate_weights_kernel(
    const float* __restrict__ logits, floatx4* __restrict__ w) {
    int g = blockIdx.x * blockDim.x + threadIdx.x;
    if (g >= NUM_GATES) return;

    const floatx4* lp = reinterpret_cast<const floatx4*>(logits + (size_t)g * 16);
    floatx4 l0 = lp[0], l1 = lp[1], l2 = lp[2], l3 = lp[3];
    float p[16];
    p[0]=l0.x;  p[1]=l0.y;  p[2]=l0.z;  p[3]=l0.w;
    p[4]=l1.x;  p[5]=l1.y;  p[6]=l1.z;  p[7]=l1.w;
    p[8]=l2.x;  p[9]=l2.y;  p[10]=l2.z; p[11]=l2.w;
    p[12]=l3.x; p[13]=l3.y; p[14]=l3.z; p[15]=l3.w;

    float m = p[0];
    #pragma unroll
    for (int i = 1; i < 16; ++i) m = fmaxf(m, p[i]);
    float s = 0.f;
    #pragma unroll
    for (int i = 0; i < 16; ++i) { p[i] = __expf(p[i] - m); s += p[i]; }
    float inv = 1.f / s;

    float c0  = p[8]+p[9]+p[10]+p[11]+p[12]+p[13]+p[14]+p[15];
    float ca  = p[2]+p[3]+p[6]+p[7] - p[8]-p[9]-p[12]-p[13];
    float cb  = p[4]+p[5]+p[6]+p[7] - p[8]-p[9]-p[10]-p[11];
    float cab = p[1]-p[2]-p[4]-2.f*p[6]-p[7]+p[8]+2.f*p[9]+p[11]+p[13]-p[14];
    floatx4 wv = { c0*inv, ca*inv, cb*inv, cab*inv };
    w[g] = wv;
}

// ---------------------------------------------------------------------------
// Kernel 2: streaming kernel, load-all-then-compute for max MLP.
// Phase A: issue 8x dwordx4 + 8x dword loads (16 outstanding vmem per wave).
// Phase B: clip + 16 fmaf per row, nontemporal 16B store.
// ---------------------------------------------------------------------------
__global__ __launch_bounds__(256) void dll_main_kernel(
    const float* __restrict__ x,
    const floatx4* __restrict__ w,
    float* __restrict__ out) {

    int tid  = blockIdx.x * blockDim.x + threadIdx.x;   // 0 .. 524287
    int col4 = tid & (V4_PER_ROW - 1);                  // fixed column slot
    int row0 = tid >> 11;                               // 0 .. 255

    int g  = col4 * 4;
    int gn = (g + 4) & (INPUT_SIZE - 1);                // wrap neighbor index

    floatx4 w0 = w[g + 0];
    floatx4 w1 = w[g + 1];
    floatx4 w2 = w[g + 2];
    floatx4 w3 = w[g + 3];

    // ---- Phase A: issue ALL loads (fully unrolled -> registers) ----------
    floatx4 xv[NITER];
    float   xn[NITER];
    #pragma unroll
    for (int it = 0; it < NITER; ++it) {
        const float* xr = x + (size_t)(row0 + it * ROW_STRIDE) * INPUT_SIZE;
        xv[it] = *reinterpret_cast<const floatx4*>(xr + g);
        xn[it] = xr[gn];
    }

    // ---- Phase B: compute + store as loads complete -----------------------
    #pragma unroll
    for (int it = 0; it < NITER; ++it) {
        int row = row0 + it * ROW_STRIDE;

        float a0 = fminf(fmaxf(xv[it].x, 0.f), 1.f);
        float a1 = fminf(fmaxf(xv[it].y, 0.f), 1.f);
        float a2 = fminf(fmaxf(xv[it].z, 0.f), 1.f);
        float a3 = fminf(fmaxf(xv[it].w, 0.f), 1.f);
        float a4 = fminf(fmaxf(xn[it],   0.f), 1.f);

        floatx4 o;
        o.x = fmaf(w0.w, a0 * a1, fmaf(w0.z, a1, fmaf(w0.y, a0, w0.x)));
        o.y = fmaf(w1.w, a1 * a2, fmaf(w1.z, a2, fmaf(w1.y, a1, w1.x)));
        o.z = fmaf(w2.w, a2 * a3, fmaf(w2.z, a3, fmaf(w2.y, a2, w2.x)));
        o.w = fmaf(w3.w, a3 * a4, fmaf(w3.z, a4, fmaf(w3.y, a3, w3.x)));

        __builtin_nontemporal_store(o,
            reinterpret_cast<floatx4*>(out + (size_t)row * INPUT_SIZE + g));
    }
}

extern "C" void kernel_launch(void* const* d_in, const int* in_sizes, int n_in,
                              void* d_out, int out_size, void* d_ws, size_t ws_size,
                              hipStream_t stream) {
    const float* x      = reinterpret_cast<const float*>(d_in[0]);
    const float* logits = reinterpret_cast<const float*>(d_in[1]);
    float*       out    = reinterpret_cast<float*>(d_out);
    floatx4*     w      = reinterpret_cast<floatx4*>(d_ws);   // 128 KB table

    gate_weights_kernel<<<NUM_GATES / 256, 256, 0, stream>>>(logits, w);
    dll_main_kernel<<<NBLOCKS, 256, 0, stream>>>(x, w, out);
}

// Round 9
// 31.050 us; speedup vs baseline: 1.0826x; 1.0826x over previous
//
#include <hip/hip_runtime.h>
#include <math.h>

// DifferentiableLogicLayer:
//   out[b,g] = c0[g] + ca[g]*a + cb[g]*b + cab[g]*a*b   (affine collapse of
//   the 16 soft-logic ops dotted with softmax(gate_logits[g]))
//   a = clip(x[b, g%8192]), b = clip(x[b, (g+1)%8192])
//
// R8 lesson: MLP restructure neutral => not latency-limited per wave.
// R9 theory: L1/TA REQUEST rate is the limiter. The scalar neighbor load
// adds 17 segment-requests per wave-row (~49 vs copy's 32 => 6.3*32/49
// ~= 4.1 TB/s, matching observed ~4 TB/s). Neighbor = next lane's xv.x:
// use __shfl_down (idle DS pipe); only lane 63 does a real load.
// Two-kernel structure kept (dedup'd softmax w-table, 128 KB, L2-resident).

constexpr int INPUT_SIZE = 8192;
constexpr int NUM_GATES  = 8192;
constexpr int BATCH      = 2048;
constexpr int V4_PER_ROW = INPUT_SIZE / 4;   // 2048 float4 per row
constexpr int NBLOCKS    = 2048;             // 524288 threads
constexpr int ROW_STRIDE = 256;              // 524288 / 2048 col slots

typedef float floatx4 __attribute__((ext_vector_type(4)));

// ---------------------------------------------------------------------------
// Kernel 1: fold softmax(gate_logits) into 4 affine coefficients per gate.
// ---------------------------------------------------------------------------
__global__ __launch_bounds__(256) void gate_weights_kernel(
    const float* __restrict__ logits, floatx4* __restrict__ w) {
    int g = blockIdx.x * blockDim.x + threadIdx.x;
    if (g >= NUM_GATES) return;

    const floatx4* lp = reinterpret_cast<const floatx4*>(logits + (size_t)g * 16);
    floatx4 l0 = lp[0], l1 = lp[1], l2 = lp[2], l3 = lp[3];
    float p[16];
    p[0]=l0.x;  p[1]=l0.y;  p[2]=l0.z;  p[3]=l0.w;
    p[4]=l1.x;  p[5]=l1.y;  p[6]=l1.z;  p[7]=l1.w;
    p[8]=l2.x;  p[9]=l2.y;  p[10]=l2.z; p[11]=l2.w;
    p[12]=l3.x; p[13]=l3.y; p[14]=l3.z; p[15]=l3.w;

    float m = p[0];
    #pragma unroll
    for (int i = 1; i < 16; ++i) m = fmaxf(m, p[i]);
    float s = 0.f;
    #pragma unroll
    for (int i = 0; i < 16; ++i) { p[i] = __expf(p[i] - m); s += p[i]; }
    float inv = 1.f / s;

    float c0  = p[8]+p[9]+p[10]+p[11]+p[12]+p[13]+p[14]+p[15];
    float ca  = p[2]+p[3]+p[6]+p[7] - p[8]-p[9]-p[12]-p[13];
    float cb  = p[4]+p[5]+p[6]+p[7] - p[8]-p[9]-p[10]-p[11];
    float cab = p[1]-p[2]-p[4]-2.f*p[6]-p[7]+p[8]+2.f*p[9]+p[11]+p[13]-p[14];
    floatx4 wv = { c0*inv, ca*inv, cb*inv, cab*inv };
    w[g] = wv;
}

// ---------------------------------------------------------------------------
// Kernel 2: streaming kernel. Per row per wave: ONE 1KB coalesced vector
// read + shuffle for the neighbor (lane 63 only: 1 predicated dword load)
// + ONE 1KB nontemporal store. ~33 L1 segments/row vs R7's ~49.
// ---------------------------------------------------------------------------
__global__ __launch_bounds__(256) void dll_main_kernel(
    const float* __restrict__ x,
    const floatx4* __restrict__ w,
    float* __restrict__ out) {

    int tid  = blockIdx.x * blockDim.x + threadIdx.x;   // 0 .. 524287
    int col4 = tid & (V4_PER_ROW - 1);                  // fixed column slot
    int row0 = tid >> 11;                               // 0 .. 255
    int lane = threadIdx.x & 63;

    int g  = col4 * 4;
    int gn = (g + 4) & (INPUT_SIZE - 1);                // wrap neighbor index

    floatx4 w0 = w[g + 0];
    floatx4 w1 = w[g + 1];
    floatx4 w2 = w[g + 2];
    floatx4 w3 = w[g + 3];

    for (int row = row0; row < BATCH; row += ROW_STRIDE) {
        const float* xr = x + (size_t)row * INPUT_SIZE;
        floatx4 xv = *reinterpret_cast<const floatx4*>(xr + g);

        // neighbor element x[row, g+4] == next lane's xv.x (except lane 63)
        float nb = __shfl_down(xv.x, 1);
        if (lane == 63) nb = xr[gn];

        float a0 = fminf(fmaxf(xv.x, 0.f), 1.f);
        float a1 = fminf(fmaxf(xv.y, 0.f), 1.f);
        float a2 = fminf(fmaxf(xv.z, 0.f), 1.f);
        float a3 = fminf(fmaxf(xv.w, 0.f), 1.f);
        float a4 = fminf(fmaxf(nb,   0.f), 1.f);

        floatx4 o;
        o.x = fmaf(w0.w, a0 * a1, fmaf(w0.z, a1, fmaf(w0.y, a0, w0.x)));
        o.y = fmaf(w1.w, a1 * a2, fmaf(w1.z, a2, fmaf(w1.y, a1, w1.x)));
        o.z = fmaf(w2.w, a2 * a3, fmaf(w2.z, a3, fmaf(w2.y, a2, w2.x)));
        o.w = fmaf(w3.w, a3 * a4, fmaf(w3.z, a4, fmaf(w3.y, a3, w3.x)));

        __builtin_nontemporal_store(o,
            reinterpret_cast<floatx4*>(out + (size_t)row * INPUT_SIZE + g));
    }
}

extern "C" void kernel_launch(void* const* d_in, const int* in_sizes, int n_in,
                              void* d_out, int out_size, void* d_ws, size_t ws_size,
                              hipStream_t stream) {
    const float* x      = reinterpret_cast<const float*>(d_in[0]);
    const float* logits = reinterpret_cast<const float*>(d_in[1]);
    float*       out    = reinterpret_cast<float*>(d_out);
    floatx4*     w      = reinterpret_cast<floatx4*>(d_ws);   // 128 KB table

    gate_weights_kernel<<<NUM_GATES / 256, 256, 0, stream>>>(logits, w);
    dll_main_kernel<<<NBLOCKS, 256, 0, stream>>>(x, w, out);
}

// Round 10
// 30.926 us; speedup vs baseline: 1.0870x; 1.0040x over previous
//
#include <hip/hip_runtime.h>
#include <math.h>

// DifferentiableLogicLayer:
//   out[b,g] = c0[g] + ca[g]*a + cb[g]*b + cab[g]*a*b   (affine collapse of
//   the 16 soft-logic ops dotted with softmax(gate_logits[g]))
//   a = clip(x[b, g%8192]), b = clip(x[b, (g+1)%8192])
//
// R9 lesson: shuffle-for-neighbor gained 1.2us (31.05us, best). Trajectory
// arithmetic: k1+gap ~1us, stream kernel ~27-30us at ~4 TB/s vs 6.3 copy
// ceiling. R10: clean A/B on the nontemporal store (introduced R7, never
// isolated). nt = no-allocate => may defeat L2 write-burst aggregation;
// fillBuffer (6.6 TB/s) and m13 copy (6.29 TB/s) both use plain stores.
// Single change vs R9: plain store.

constexpr int INPUT_SIZE = 8192;
constexpr int NUM_GATES  = 8192;
constexpr int BATCH      = 2048;
constexpr int V4_PER_ROW = INPUT_SIZE / 4;   // 2048 float4 per row
constexpr int NBLOCKS    = 2048;             // 524288 threads
constexpr int ROW_STRIDE = 256;              // 524288 / 2048 col slots

typedef float floatx4 __attribute__((ext_vector_type(4)));

// ---------------------------------------------------------------------------
// Kernel 1: fold softmax(gate_logits) into 4 affine coefficients per gate.
// ---------------------------------------------------------------------------
__global__ __launch_bounds__(256) void gate_weights_kernel(
    const float* __restrict__ logits, floatx4* __restrict__ w) {
    int g = blockIdx.x * blockDim.x + threadIdx.x;
    if (g >= NUM_GATES) return;

    const floatx4* lp = reinterpret_cast<const floatx4*>(logits + (size_t)g * 16);
    floatx4 l0 = lp[0], l1 = lp[1], l2 = lp[2], l3 = lp[3];
    float p[16];
    p[0]=l0.x;  p[1]=l0.y;  p[2]=l0.z;  p[3]=l0.w;
    p[4]=l1.x;  p[5]=l1.y;  p[6]=l1.z;  p[7]=l1.w;
    p[8]=l2.x;  p[9]=l2.y;  p[10]=l2.z; p[11]=l2.w;
    p[12]=l3.x; p[13]=l3.y; p[14]=l3.z; p[15]=l3.w;

    float m = p[0];
    #pragma unroll
    for (int i = 1; i < 16; ++i) m = fmaxf(m, p[i]);
    float s = 0.f;
    #pragma unroll
    for (int i = 0; i < 16; ++i) { p[i] = __expf(p[i] - m); s += p[i]; }
    float inv = 1.f / s;

    float c0  = p[8]+p[9]+p[10]+p[11]+p[12]+p[13]+p[14]+p[15];
    float ca  = p[2]+p[3]+p[6]+p[7] - p[8]-p[9]-p[12]-p[13];
    float cb  = p[4]+p[5]+p[6]+p[7] - p[8]-p[9]-p[10]-p[11];
    float cab = p[1]-p[2]-p[4]-2.f*p[6]-p[7]+p[8]+2.f*p[9]+p[11]+p[13]-p[14];
    floatx4 wv = { c0*inv, ca*inv, cb*inv, cab*inv };
    w[g] = wv;
}

// ---------------------------------------------------------------------------
// Kernel 2: streaming kernel. Per row per wave: ONE 1KB coalesced vector
// read + shuffle for the neighbor (lane 63 only: 1 predicated dword load)
// + ONE 1KB plain store (A/B vs R9's nontemporal).
// ---------------------------------------------------------------------------
__global__ __launch_bounds__(256) void dll_main_kernel(
    const float* __restrict__ x,
    const floatx4* __restrict__ w,
    float* __restrict__ out) {

    int tid  = blockIdx.x * blockDim.x + threadIdx.x;   // 0 .. 524287
    int col4 = tid & (V4_PER_ROW - 1);                  // fixed column slot
    int row0 = tid >> 11;                               // 0 .. 255
    int lane = threadIdx.x & 63;

    int g  = col4 * 4;
    int gn = (g + 4) & (INPUT_SIZE - 1);                // wrap neighbor index

    floatx4 w0 = w[g + 0];
    floatx4 w1 = w[g + 1];
    floatx4 w2 = w[g + 2];
    floatx4 w3 = w[g + 3];

    for (int row = row0; row < BATCH; row += ROW_STRIDE) {
        const float* xr = x + (size_t)row * INPUT_SIZE;
        floatx4 xv = *reinterpret_cast<const floatx4*>(xr + g);

        // neighbor element x[row, g+4] == next lane's xv.x (except lane 63)
        float nb = __shfl_down(xv.x, 1);
        if (lane == 63) nb = xr[gn];

        float a0 = fminf(fmaxf(xv.x, 0.f), 1.f);
        float a1 = fminf(fmaxf(xv.y, 0.f), 1.f);
        float a2 = fminf(fmaxf(xv.z, 0.f), 1.f);
        float a3 = fminf(fmaxf(xv.w, 0.f), 1.f);
        float a4 = fminf(fmaxf(nb,   0.f), 1.f);

        floatx4 o;
        o.x = fmaf(w0.w, a0 * a1, fmaf(w0.z, a1, fmaf(w0.y, a0, w0.x)));
        o.y = fmaf(w1.w, a1 * a2, fmaf(w1.z, a2, fmaf(w1.y, a1, w1.x)));
        o.z = fmaf(w2.w, a2 * a3, fmaf(w2.z, a3, fmaf(w2.y, a2, w2.x)));
        o.w = fmaf(w3.w, a3 * a4, fmaf(w3.z, a4, fmaf(w3.y, a3, w3.x)));

        *reinterpret_cast<floatx4*>(out + (size_t)row * INPUT_SIZE + g) = o;
    }
}

extern "C" void kernel_launch(void* const* d_in, const int* in_sizes, int n_in,
                              void* d_out, int out_size, void* d_ws, size_t ws_size,
                              hipStream_t stream) {
    const float* x      = reinterpret_cast<const float*>(d_in[0]);
    const float* logits = reinterpret_cast<const float*>(d_in[1]);
    float*       out    = reinterpret_cast<float*>(d_out);
    floatx4*     w      = reinterpret_cast<floatx4*>(d_ws);   // 128 KB table

    gate_weights_kernel<<<NUM_GATES / 256, 256, 0, stream>>>(logits, w);
    dll_main_kernel<<<NBLOCKS, 256, 0, stream>>>(x, w, out);
}